// Round 1
// baseline (363.164 us; speedup 1.0000x reference)
//
#include <hip/hip_runtime.h>

#define N_NODES 50000
#define N_EDGES 800000
#define D 128
#define BM 64
#define BK 16

// ---------- CSR build ----------
__global__ void k_hist(const int* __restrict__ dst, int* __restrict__ deg) {
    int i = blockIdx.x * blockDim.x + threadIdx.x;
    if (i < N_EDGES) atomicAdd(&deg[dst[i]], 1);
}

__global__ void k_scan(const int* __restrict__ deg, int* __restrict__ row_ptr) {
    __shared__ int wsum[16];
    __shared__ int woff[16];
    const int tid  = threadIdx.x;    // 1024 threads
    const int lane = tid & 63;
    const int wid  = tid >> 6;
    int carry = 0;
    for (int base = 0; base < N_NODES; base += 1024) {
        int i = base + tid;
        int v = (i < N_NODES) ? deg[i] : 0;
        int incl = v;
        #pragma unroll
        for (int off = 1; off < 64; off <<= 1) {
            int t = __shfl_up(incl, off);
            if (lane >= off) incl += t;
        }
        if (lane == 63) wsum[wid] = incl;
        __syncthreads();
        if (wid == 0) {
            int s = (lane < 16) ? wsum[lane] : 0;
            #pragma unroll
            for (int off = 1; off < 16; off <<= 1) {
                int t = __shfl_up(s, off);
                if (lane >= off) s += t;
            }
            if (lane < 16) woff[lane] = s;  // inclusive over waves
        }
        __syncthreads();
        int wexcl = (wid == 0) ? 0 : woff[wid - 1];
        int total = woff[15];
        if (i < N_NODES) row_ptr[i] = carry + wexcl + incl - v;
        carry += total;
        __syncthreads();
    }
    if (tid == 0) row_ptr[N_NODES] = carry;
}

__global__ void k_scatter(const int* __restrict__ src, const int* __restrict__ dst,
                          const int* __restrict__ row_ptr, int* __restrict__ fill,
                          int* __restrict__ edge_src) {
    int i = blockIdx.x * blockDim.x + threadIdx.x;
    if (i < N_EDGES) {
        int d = dst[i];
        int pos = atomicSub(&fill[d], 1) - 1;   // fill==deg counts down to 0
        edge_src[row_ptr[d] + pos] = src[i];
    }
}

// ---------- mean aggregation: one wave per node, lane owns 2 cols ----------
__global__ __launch_bounds__(256) void k_agg(const float* __restrict__ xin,
                                             const int* __restrict__ row_ptr,
                                             const int* __restrict__ edge_src,
                                             float* __restrict__ agg) {
    int node = (blockIdx.x * blockDim.x + threadIdx.x) >> 6;
    int lane = threadIdx.x & 63;
    if (node >= N_NODES) return;
    int beg = row_ptr[node], end = row_ptr[node + 1];
    float2 acc = {0.f, 0.f};
    int e = beg;
    for (; e + 1 < end; e += 2) {
        int s0 = edge_src[e];
        int s1 = edge_src[e + 1];
        float2 a = *(const float2*)&xin[(size_t)s0 * D + lane * 2];
        float2 b = *(const float2*)&xin[(size_t)s1 * D + lane * 2];
        acc.x += a.x + b.x;
        acc.y += a.y + b.y;
    }
    if (e < end) {
        int s0 = edge_src[e];
        float2 a = *(const float2*)&xin[(size_t)s0 * D + lane * 2];
        acc.x += a.x;
        acc.y += a.y;
    }
    int dg = end - beg;
    float inv = 1.0f / (float)(dg > 1 ? dg : 1);
    float2 r = {acc.x * inv, acc.y * inv};
    *(float2*)&agg[(size_t)node * D + lane * 2] = r;
}

// ---------- fused out = relu([agg|x] @ [Wn;Wr] + b), reg-tiled fp32 ----------
__global__ __launch_bounds__(256) void k_gemm(const float* __restrict__ agg,
                                              const float* __restrict__ xin,
                                              const float* __restrict__ Wn,
                                              const float* __restrict__ Wr,
                                              const float* __restrict__ bias,
                                              float* __restrict__ out) {
    __shared__ float Asm[BK][BM];   // transposed A tile
    __shared__ float Wsm[BK][D];
    const int tid = threadIdx.x;
    const int tx = tid & 31;        // col group: cols [tx*4, tx*4+3]
    const int ty = tid >> 5;        // node group: nodes [ty*8, ty*8+7]
    const int n0 = blockIdx.x * BM;

    float acc[8][4];
    #pragma unroll
    for (int i = 0; i < 8; i++)
        #pragma unroll
        for (int j = 0; j < 4; j++) acc[i][j] = 0.f;

    for (int k0 = 0; k0 < 2 * D; k0 += BK) {
        const float* Asrc = (k0 < D) ? agg : xin;
        const float* Wsrc = (k0 < D) ? Wn : Wr;
        const int kk0 = (k0 < D) ? k0 : (k0 - D);
        // stage A (64x16), row-major load -> transposed store
        {
            int e = tid * 4;
            int i = e / BK;               // tid/4: node within tile
            int k = e % BK;               // (tid%4)*4
            int nn = n0 + i; if (nn >= N_NODES) nn = N_NODES - 1;
            float4 a = *(const float4*)&Asrc[(size_t)nn * D + kk0 + k];
            Asm[k][i] = a.x; Asm[k + 1][i] = a.y; Asm[k + 2][i] = a.z; Asm[k + 3][i] = a.w;
        }
        // stage W (16x128)
        {
            int e = tid * 8;
            int k = e / D;                // tid/16
            int j = e % D;                // (tid%16)*8
            float4 w0 = *(const float4*)&Wsrc[(size_t)(kk0 + k) * D + j];
            float4 w1 = *(const float4*)&Wsrc[(size_t)(kk0 + k) * D + j + 4];
            *(float4*)&Wsm[k][j] = w0;
            *(float4*)&Wsm[k][j + 4] = w1;
        }
        __syncthreads();
        #pragma unroll
        for (int kk = 0; kk < BK; kk++) {
            float4 w  = *(const float4*)&Wsm[kk][tx * 4];
            float4 a0 = *(const float4*)&Asm[kk][ty * 8];
            float4 a1 = *(const float4*)&Asm[kk][ty * 8 + 4];
            float av[8] = {a0.x, a0.y, a0.z, a0.w, a1.x, a1.y, a1.z, a1.w};
            #pragma unroll
            for (int i = 0; i < 8; i++) {
                acc[i][0] = fmaf(av[i], w.x, acc[i][0]);
                acc[i][1] = fmaf(av[i], w.y, acc[i][1]);
                acc[i][2] = fmaf(av[i], w.z, acc[i][2]);
                acc[i][3] = fmaf(av[i], w.w, acc[i][3]);
            }
        }
        __syncthreads();
    }
    float4 bv = *(const float4*)&bias[tx * 4];
    #pragma unroll
    for (int i = 0; i < 8; i++) {
        int n = n0 + ty * 8 + i;
        if (n < N_NODES) {
            float4 r;
            r.x = fmaxf(acc[i][0] + bv.x, 0.f);
            r.y = fmaxf(acc[i][1] + bv.y, 0.f);
            r.z = fmaxf(acc[i][2] + bv.z, 0.f);
            r.w = fmaxf(acc[i][3] + bv.w, 0.f);
            *(float4*)&out[(size_t)n * D + tx * 4] = r;
        }
    }
}

extern "C" void kernel_launch(void* const* d_in, const int* in_sizes, int n_in,
                              void* d_out, int out_size, void* d_ws, size_t ws_size,
                              hipStream_t stream) {
    const float* x   = (const float*)d_in[0];
    const int*   ei  = (const int*)d_in[1];
    const float* Wn1 = (const float*)d_in[2];
    const float* Wr1 = (const float*)d_in[3];
    const float* b1  = (const float*)d_in[4];
    const float* Wn2 = (const float*)d_in[5];
    const float* Wr2 = (const float*)d_in[6];
    const float* b2  = (const float*)d_in[7];
    float* out = (float*)d_out;

    const int* src = ei;             // edge_index[0]
    const int* dst = ei + N_EDGES;   // edge_index[1]

    char* w = (char*)d_ws;
    float* agg     = (float*)w;                                   // N*D f32 (25.6MB)
    int*   row_ptr = (int*)(w + (size_t)N_NODES * D * 4);         // N+1
    int*   deg     = row_ptr + N_NODES + 4;                       // N (also fill)
    int*   edge_src = deg + N_NODES + 4;                          // E

    hipMemsetAsync(deg, 0, N_NODES * sizeof(int), stream);
    k_hist<<<(N_EDGES + 255) / 256, 256, 0, stream>>>(dst, deg);
    k_scan<<<1, 1024, 0, stream>>>(deg, row_ptr);
    k_scatter<<<(N_EDGES + 255) / 256, 256, 0, stream>>>(src, dst, row_ptr, deg, edge_src);

    const int aggGrid  = (N_NODES * 64) / 256;          // one wave per node
    const int gemmGrid = (N_NODES + BM - 1) / BM;

    // layer 1: hid lives in d_out
    k_agg<<<aggGrid, 256, 0, stream>>>(x, row_ptr, edge_src, agg);
    k_gemm<<<gemmGrid, 256, 0, stream>>>(agg, x, Wn1, Wr1, b1, out);
    // layer 2: in-place on d_out (per-block rows only)
    k_agg<<<aggGrid, 256, 0, stream>>>(out, row_ptr, edge_src, agg);
    k_gemm<<<gemmGrid, 256, 0, stream>>>(agg, out, Wn2, Wr2, b2, out);
}

// Round 2
// 251.492 us; speedup vs baseline: 1.4440x; 1.4440x over previous
//
#include <hip/hip_runtime.h>

#define N_NODES 50000
#define N_EDGES 800000
#define D 128

typedef __attribute__((ext_vector_type(8))) short bf16x8;
typedef __attribute__((ext_vector_type(4))) float f32x4;

__device__ __forceinline__ unsigned short f2bf(float f) {
    unsigned u = __float_as_uint(f);
    unsigned r = (u + 0x7FFFu + ((u >> 16) & 1u)) >> 16;   // RNE
    return (unsigned short)r;
}
__device__ __forceinline__ float bf2f(unsigned short h) {
    return __uint_as_float(((unsigned)h) << 16);
}

// ---------- f32 -> bf16 conversion (8 elems/thread) ----------
__global__ __launch_bounds__(256) void k_cvt(const float* __restrict__ in,
                                             ushort* __restrict__ out, int n8) {
    int i = blockIdx.x * blockDim.x + threadIdx.x;
    if (i >= n8) return;
    const float4* p = (const float4*)(in + (size_t)i * 8);
    float4 a = p[0], b = p[1];
    uint4 o;
    o.x = (unsigned)f2bf(a.x) | ((unsigned)f2bf(a.y) << 16);
    o.y = (unsigned)f2bf(a.z) | ((unsigned)f2bf(a.w) << 16);
    o.z = (unsigned)f2bf(b.x) | ((unsigned)f2bf(b.y) << 16);
    o.w = (unsigned)f2bf(b.z) | ((unsigned)f2bf(b.w) << 16);
    *(uint4*)(out + (size_t)i * 8) = o;
}

// ---------- pack W = [Wn;Wr] (256x128) into MFMA B-fragment layout ----------
// Wp[((ks*128 + c)*4 + g)*8 + i] = W[ks*32 + g*8 + i][c]
__global__ __launch_bounds__(256) void k_pack(const float* __restrict__ Wn,
                                              const float* __restrict__ Wr,
                                              ushort* __restrict__ Wp) {
    int t = blockIdx.x * blockDim.x + threadIdx.x;
    if (t >= 256 * 128) return;
    int k = t >> 7, c = t & 127;
    float v = (k < 128) ? Wn[k * 128 + c] : Wr[(k - 128) * 128 + c];
    int ks = k >> 5, g = (k >> 3) & 3, i = k & 7;
    Wp[(((ks * 128 + c) * 4 + g) << 3) + i] = f2bf(v);
}

// ---------- CSR build ----------
__global__ __launch_bounds__(256) void k_hist(const int* __restrict__ dst,
                                              int* __restrict__ deg) {
    int i = blockIdx.x * blockDim.x + threadIdx.x;
    if (i < N_EDGES) atomicAdd(&deg[dst[i]], 1);
}

__global__ __launch_bounds__(1024) void k_scan1(const int* __restrict__ deg,
                                                int* __restrict__ row_ptr,
                                                int* __restrict__ bsum) {
    __shared__ int wsum[16], woff[16];
    const int tid = threadIdx.x, lane = tid & 63, wid = tid >> 6;
    int i = blockIdx.x * 1024 + tid;
    int v = (i < N_NODES) ? deg[i] : 0;
    int incl = v;
    #pragma unroll
    for (int off = 1; off < 64; off <<= 1) {
        int t = __shfl_up(incl, off);
        if (lane >= off) incl += t;
    }
    if (lane == 63) wsum[wid] = incl;
    __syncthreads();
    if (wid == 0) {
        int s = (lane < 16) ? wsum[lane] : 0;
        #pragma unroll
        for (int off = 1; off < 16; off <<= 1) {
            int t = __shfl_up(s, off);
            if (lane >= off) s += t;
        }
        if (lane < 16) woff[lane] = s;
    }
    __syncthreads();
    int wexcl = wid ? woff[wid - 1] : 0;
    if (i < N_NODES) row_ptr[i] = wexcl + incl - v;
    if (tid == 1023) bsum[blockIdx.x] = woff[15];
}

__global__ void k_scan2(const int* __restrict__ bsum, int* __restrict__ boff,
                        int* __restrict__ row_ptr_end, int nb) {
    int lane = threadIdx.x;
    int v = (lane < nb) ? bsum[lane] : 0;
    int incl = v;
    #pragma unroll
    for (int off = 1; off < 64; off <<= 1) {
        int t = __shfl_up(incl, off);
        if (lane >= off) incl += t;
    }
    if (lane < nb) boff[lane] = incl - v;
    if (lane == 63) *row_ptr_end = incl;
}

__global__ __launch_bounds__(1024) void k_scan3(int* __restrict__ row_ptr,
                                                const int* __restrict__ boff) {
    int i = blockIdx.x * 1024 + threadIdx.x;
    if (i < N_NODES) row_ptr[i] += boff[blockIdx.x];
}

__global__ __launch_bounds__(256) void k_scatter(const int* __restrict__ src,
                                                 const int* __restrict__ dst,
                                                 const int* __restrict__ row_ptr,
                                                 int* __restrict__ fill,
                                                 int* __restrict__ edge_src) {
    int i = blockIdx.x * blockDim.x + threadIdx.x;
    if (i < N_EDGES) {
        int d = dst[i];
        int pos = atomicSub(&fill[d], 1) - 1;
        edge_src[row_ptr[d] + pos] = src[i];
    }
}

// ---------- mean aggregation: one wave/node, half-wave/edge, bf16 rows ----------
__global__ __launch_bounds__(256) void k_agg(const ushort* __restrict__ xb,
                                             const int* __restrict__ row_ptr,
                                             const int* __restrict__ edge_src,
                                             ushort* __restrict__ aggb) {
    int node = (blockIdx.x * blockDim.x + threadIdx.x) >> 6;
    int lane = threadIdx.x & 63;
    if (node >= N_NODES) return;
    int beg = row_ptr[node], end = row_ptr[node + 1];
    const int half = lane >> 5;
    const int c4 = (lane & 31) * 4;
    float ax = 0.f, ay = 0.f, az = 0.f, aw = 0.f;
    for (int e = beg; e < end; e += 2) {
        int ee = e + half;
        if (ee < end) {
            int s = edge_src[ee];
            ushort4 v = *(const ushort4*)&xb[(size_t)s * D + c4];
            ax += bf2f(v.x); ay += bf2f(v.y); az += bf2f(v.z); aw += bf2f(v.w);
        }
    }
    ax += __shfl_xor(ax, 32);
    ay += __shfl_xor(ay, 32);
    az += __shfl_xor(az, 32);
    aw += __shfl_xor(aw, 32);
    if (half == 0) {
        int dg = end - beg;
        float inv = 1.0f / (float)(dg > 1 ? dg : 1);
        ushort4 o;
        o.x = f2bf(ax * inv); o.y = f2bf(ay * inv);
        o.z = f2bf(az * inv); o.w = f2bf(aw * inv);
        *(ushort4*)&aggb[(size_t)node * D + c4] = o;
    }
}

// ---------- MFMA GEMM: out = relu([agg|xroot] @ [Wn;Wr] + b) ----------
// block = 128 thr (2 waves), tile 64 rows x 128 cols; wave wid owns cols [wid*64,+64)
// K = 256 in 8 steps of 32; A,B fragments loaded straight from global (no LDS).
template <int OUT_F32>
__global__ __launch_bounds__(128) void k_gemm(const ushort* __restrict__ Ab,
                                              const ushort* __restrict__ Xb,
                                              const ushort* __restrict__ Wp,
                                              const float* __restrict__ bias,
                                              void* __restrict__ outv) {
    const int lane = threadIdx.x & 63;
    const int wid  = threadIdx.x >> 6;
    const int row0 = blockIdx.x * 64;
    const int col0 = wid * 64;
    const int r = lane & 15, g = lane >> 4;

    f32x4 acc[4][4] = {};
    #pragma unroll
    for (int ks = 0; ks < 8; ks++) {
        const ushort* As = (ks < 4) ? Ab : Xb;
        const int kk = (ks & 3) * 32 + 8 * g;
        bf16x8 a[4], b[4];
        #pragma unroll
        for (int rf = 0; rf < 4; rf++) {
            int rr = row0 + rf * 16 + r;
            if (rr > N_NODES - 1) rr = N_NODES - 1;
            a[rf] = *(const bf16x8*)&As[(size_t)rr * D + kk];
        }
        #pragma unroll
        for (int cf = 0; cf < 4; cf++) {
            int c = col0 + cf * 16 + r;
            b[cf] = *(const bf16x8*)&Wp[(((size_t)ks * 128 + c) * 4 + g) * 8];
        }
        #pragma unroll
        for (int rf = 0; rf < 4; rf++)
            #pragma unroll
            for (int cf = 0; cf < 4; cf++)
                acc[rf][cf] = __builtin_amdgcn_mfma_f32_16x16x32_bf16(
                    a[rf], b[cf], acc[rf][cf], 0, 0, 0);
    }
    float bv[4];
    #pragma unroll
    for (int cf = 0; cf < 4; cf++) bv[cf] = bias[col0 + cf * 16 + r];
    #pragma unroll
    for (int rf = 0; rf < 4; rf++) {
        #pragma unroll
        for (int j = 0; j < 4; j++) {
            int row = row0 + rf * 16 + g * 4 + j;
            if (row < N_NODES) {
                #pragma unroll
                for (int cf = 0; cf < 4; cf++) {
                    float v = fmaxf(acc[rf][cf][j] + bv[cf], 0.f);
                    int col = col0 + cf * 16 + r;
                    if (OUT_F32) ((float*)outv)[(size_t)row * D + col] = v;
                    else ((ushort*)outv)[(size_t)row * D + col] = f2bf(v);
                }
            }
        }
    }
}

extern "C" void kernel_launch(void* const* d_in, const int* in_sizes, int n_in,
                              void* d_out, int out_size, void* d_ws, size_t ws_size,
                              hipStream_t stream) {
    const float* x   = (const float*)d_in[0];
    const int*   ei  = (const int*)d_in[1];
    const float* Wn1 = (const float*)d_in[2];
    const float* Wr1 = (const float*)d_in[3];
    const float* b1  = (const float*)d_in[4];
    const float* Wn2 = (const float*)d_in[5];
    const float* Wr2 = (const float*)d_in[6];
    const float* b2  = (const float*)d_in[7];
    float* out = (float*)d_out;

    const int* src = ei;
    const int* dst = ei + N_EDGES;

    const size_t bfb = (size_t)N_NODES * D * 2;          // 12.8 MB
    const size_t packb = 256 * 128 * 2;                  // 64 KB
    auto au = [](size_t v) { return (v + 255) & ~(size_t)255; };

    char* w = (char*)d_ws;
    size_t o = 0;
    ushort* aggb = (ushort*)(w + o); o += au(bfb);
    ushort* hb   = (ushort*)(w + o); o += au(bfb);
    int* edge_src = (int*)(w + o);   o += au((size_t)N_EDGES * 4);
    ushort* Wp2  = (ushort*)(w + o); o += au(packb);

    size_t rem = au(bfb) + au(packb) + au((N_NODES + 1) * 4ull) +
                 au(N_NODES * 4ull) + 2 * au(64 * 4);
    ushort *xb, *Wp1;
    int *row_ptr, *deg, *bsum, *boff;
    if (ws_size >= o + rem) {
        xb = (ushort*)(w + o);      o += au(bfb);
        Wp1 = (ushort*)(w + o);     o += au(packb);
        row_ptr = (int*)(w + o);    o += au((N_NODES + 1) * 4ull);
        deg = (int*)(w + o);        o += au(N_NODES * 4ull);
        bsum = (int*)(w + o);       o += au(64 * 4);
        boff = (int*)(w + o);
    } else {
        // stash build-time data in d_out; all of it is dead before the final
        // GEMM (which reads only ws + d_in) rewrites d_out in full.
        char* q = (char*)d_out;
        size_t p = 0;
        xb = (ushort*)(q + p);      p += au(bfb);
        Wp1 = (ushort*)(q + p);     p += au(packb);
        row_ptr = (int*)(q + p);    p += au((N_NODES + 1) * 4ull);
        deg = (int*)(q + p);        p += au(N_NODES * 4ull);
        bsum = (int*)(q + p);       p += au(64 * 4);
        boff = (int*)(q + p);
    }

    hipMemsetAsync(deg, 0, N_NODES * sizeof(int), stream);
    k_cvt<<<(N_NODES * D / 8 + 255) / 256, 256, 0, stream>>>(x, xb, N_NODES * D / 8);
    k_pack<<<(256 * 128 + 255) / 256, 256, 0, stream>>>(Wn1, Wr1, Wp1);
    k_pack<<<(256 * 128 + 255) / 256, 256, 0, stream>>>(Wn2, Wr2, Wp2);

    k_hist<<<(N_EDGES + 255) / 256, 256, 0, stream>>>(dst, deg);
    const int nb = (N_NODES + 1023) / 1024;              // 49
    k_scan1<<<nb, 1024, 0, stream>>>(deg, row_ptr, bsum);
    k_scan2<<<1, 64, 0, stream>>>(bsum, boff, row_ptr + N_NODES, nb);
    k_scan3<<<nb, 1024, 0, stream>>>(row_ptr, boff);
    k_scatter<<<(N_EDGES + 255) / 256, 256, 0, stream>>>(src, dst, row_ptr, deg, edge_src);

    const int aggGrid = (N_NODES * 64) / 256;            // one wave per node
    const int gemmGrid = (N_NODES + 63) / 64;            // 782

    k_agg<<<aggGrid, 256, 0, stream>>>(xb, row_ptr, edge_src, aggb);
    k_gemm<0><<<gemmGrid, 128, 0, stream>>>(aggb, xb, Wp1, b1, hb);
    k_agg<<<aggGrid, 256, 0, stream>>>(hb, row_ptr, edge_src, aggb);
    k_gemm<1><<<gemmGrid, 128, 0, stream>>>(aggb, hb, Wp2, b2, out);
}

// Round 3
// 184.716 us; speedup vs baseline: 1.9661x; 1.3615x over previous
//
#include <hip/hip_runtime.h>

#define N_NODES 50000
#define N_EDGES 800000
#define D 128

typedef __attribute__((ext_vector_type(8))) short bf16x8;
typedef __attribute__((ext_vector_type(4))) float f32x4;

__device__ __forceinline__ unsigned short f2bf(float f) {
    unsigned u = __float_as_uint(f);
    unsigned r = (u + 0x7FFFu + ((u >> 16) & 1u)) >> 16;   // RNE
    return (unsigned short)r;
}
__device__ __forceinline__ float bf2f(unsigned short h) {
    return __uint_as_float(((unsigned)h) << 16);
}

// ---------- fused prep: x->bf16 cvt | W packs | degree histogram ----------
#define CVT_BLKS 3125                    // 50000*128/8 / 256
#define PACK_BLKS 128                    // 256*128 / 256
#define HIST_BLKS 3125                   // 800000 / 256

__device__ __forceinline__ void pack_one(const float* __restrict__ Wn,
                                         const float* __restrict__ Wr,
                                         ushort* __restrict__ Wp, int t) {
    int k = t >> 7, c = t & 127;
    float v = (k < 128) ? Wn[k * 128 + c] : Wr[(k - 128) * 128 + c];
    int ks = k >> 5, g = (k >> 3) & 3, i = k & 7;
    Wp[(((ks * 128 + c) * 4 + g) << 3) + i] = f2bf(v);
}

__global__ __launch_bounds__(256) void k_prep(const float* __restrict__ x,
                                              ushort* __restrict__ xb,
                                              const float* __restrict__ Wn1,
                                              const float* __restrict__ Wr1,
                                              ushort* __restrict__ Wp1,
                                              const float* __restrict__ Wn2,
                                              const float* __restrict__ Wr2,
                                              ushort* __restrict__ Wp2,
                                              const int* __restrict__ dst,
                                              int* __restrict__ deg) {
    int b = blockIdx.x;
    if (b < CVT_BLKS) {
        int i = b * 256 + threadIdx.x;               // 8 f32 per thread
        const float4* p = (const float4*)(x + (size_t)i * 8);
        float4 a = p[0], c = p[1];
        uint4 o;
        o.x = (unsigned)f2bf(a.x) | ((unsigned)f2bf(a.y) << 16);
        o.y = (unsigned)f2bf(a.z) | ((unsigned)f2bf(a.w) << 16);
        o.z = (unsigned)f2bf(c.x) | ((unsigned)f2bf(c.y) << 16);
        o.w = (unsigned)f2bf(c.z) | ((unsigned)f2bf(c.w) << 16);
        *(uint4*)(xb + (size_t)i * 8) = o;
    } else if (b < CVT_BLKS + PACK_BLKS) {
        int t = (b - CVT_BLKS) * 256 + threadIdx.x;  // 0..32767
        pack_one(Wn1, Wr1, Wp1, t);
        pack_one(Wn2, Wr2, Wp2, t);
    } else {
        int i = (b - CVT_BLKS - PACK_BLKS) * 256 + threadIdx.x;
        if (i < N_EDGES) atomicAdd(&deg[dst[i]], 1);
    }
}

// ---------- 3-phase scan ----------
__global__ __launch_bounds__(1024) void k_scan1(const int* __restrict__ deg,
                                                int* __restrict__ row_ptr,
                                                int* __restrict__ bsum) {
    __shared__ int wsum[16], woff[16];
    const int tid = threadIdx.x, lane = tid & 63, wid = tid >> 6;
    int i = blockIdx.x * 1024 + tid;
    int v = (i < N_NODES) ? deg[i] : 0;
    int incl = v;
    #pragma unroll
    for (int off = 1; off < 64; off <<= 1) {
        int t = __shfl_up(incl, off);
        if (lane >= off) incl += t;
    }
    if (lane == 63) wsum[wid] = incl;
    __syncthreads();
    if (wid == 0) {
        int s = (lane < 16) ? wsum[lane] : 0;
        #pragma unroll
        for (int off = 1; off < 16; off <<= 1) {
            int t = __shfl_up(s, off);
            if (lane >= off) s += t;
        }
        if (lane < 16) woff[lane] = s;
    }
    __syncthreads();
    int wexcl = wid ? woff[wid - 1] : 0;
    if (i < N_NODES) row_ptr[i] = wexcl + incl - v;
    if (tid == 1023) bsum[blockIdx.x] = woff[15];
}

__global__ void k_scan2(const int* __restrict__ bsum, int* __restrict__ boff,
                        int* __restrict__ row_ptr_end, int nb) {
    int lane = threadIdx.x;
    int v = (lane < nb) ? bsum[lane] : 0;
    int incl = v;
    #pragma unroll
    for (int off = 1; off < 64; off <<= 1) {
        int t = __shfl_up(incl, off);
        if (lane >= off) incl += t;
    }
    if (lane < nb) boff[lane] = incl - v;
    if (lane == 63) *row_ptr_end = incl;
}

__global__ __launch_bounds__(1024) void k_scan3(int* __restrict__ row_ptr,
                                                const int* __restrict__ boff) {
    int i = blockIdx.x * 1024 + threadIdx.x;
    if (i < N_NODES) row_ptr[i] += boff[blockIdx.x];
}

// ---------- countdown scatter (edge ids as uint16) ----------
__global__ __launch_bounds__(256) void k_scatter(const int* __restrict__ src,
                                                 const int* __restrict__ dst,
                                                 const int* __restrict__ row_ptr,
                                                 int* __restrict__ fill,
                                                 ushort* __restrict__ edge_src) {
    int i = blockIdx.x * blockDim.x + threadIdx.x;
    if (i < N_EDGES) {
        int d = dst[i];
        int pos = atomicSub(&fill[d], 1) - 1;
        edge_src[row_ptr[d] + pos] = (ushort)src[i];
    }
}

// ---------- mean aggregation: one wave/node, 16 lanes/edge, 4 edges in flight ----------
__global__ __launch_bounds__(256) void k_agg(const ushort* __restrict__ xb,
                                             const int* __restrict__ row_ptr,
                                             const ushort* __restrict__ edge_src,
                                             ushort* __restrict__ aggb) {
    int node = (blockIdx.x * blockDim.x + threadIdx.x) >> 6;
    int lane = threadIdx.x & 63;
    if (node >= N_NODES) return;
    int beg = row_ptr[node], end = row_ptr[node + 1];
    const int g  = lane >> 4;          // edge slot 0..3
    const int c8 = (lane & 15) * 8;    // col base
    float acc[8] = {};
    #pragma unroll 2
    for (int e = beg; e < end; e += 4) {
        int ee = e + g;
        int eec = ee < end ? ee : end - 1;
        float s = ee < end ? 1.f : 0.f;
        int sid = edge_src[eec];
        bf16x8 v = *(const bf16x8*)&xb[(size_t)sid * D + c8];
        #pragma unroll
        for (int j = 0; j < 8; j++)
            acc[j] = fmaf(bf2f((unsigned short)v[j]), s, acc[j]);
    }
    #pragma unroll
    for (int j = 0; j < 8; j++) acc[j] += __shfl_xor(acc[j], 16);
    #pragma unroll
    for (int j = 0; j < 8; j++) acc[j] += __shfl_xor(acc[j], 32);
    if (lane < 16) {
        int dg = end - beg;
        float inv = 1.0f / (float)(dg > 1 ? dg : 1);
        uint4 o;
        o.x = (unsigned)f2bf(acc[0] * inv) | ((unsigned)f2bf(acc[1] * inv) << 16);
        o.y = (unsigned)f2bf(acc[2] * inv) | ((unsigned)f2bf(acc[3] * inv) << 16);
        o.z = (unsigned)f2bf(acc[4] * inv) | ((unsigned)f2bf(acc[5] * inv) << 16);
        o.w = (unsigned)f2bf(acc[6] * inv) | ((unsigned)f2bf(acc[7] * inv) << 16);
        *(uint4*)&aggb[(size_t)node * D + c8] = o;
    }
}

// ---------- MFMA GEMM: out = relu([agg|xroot] @ [Wn;Wr] + b) ----------
template <int OUT_F32>
__global__ __launch_bounds__(128) void k_gemm(const ushort* __restrict__ Ab,
                                              const ushort* __restrict__ Xb,
                                              const ushort* __restrict__ Wp,
                                              const float* __restrict__ bias,
                                              void* __restrict__ outv) {
    const int lane = threadIdx.x & 63;
    const int wid  = threadIdx.x >> 6;
    const int row0 = blockIdx.x * 64;
    const int col0 = wid * 64;
    const int r = lane & 15, g = lane >> 4;

    f32x4 acc[4][4] = {};
    #pragma unroll
    for (int ks = 0; ks < 8; ks++) {
        const ushort* As = (ks < 4) ? Ab : Xb;
        const int kk = (ks & 3) * 32 + 8 * g;
        bf16x8 a[4], b[4];
        #pragma unroll
        for (int rf = 0; rf < 4; rf++) {
            int rr = row0 + rf * 16 + r;
            if (rr > N_NODES - 1) rr = N_NODES - 1;
            a[rf] = *(const bf16x8*)&As[(size_t)rr * D + kk];
        }
        #pragma unroll
        for (int cf = 0; cf < 4; cf++) {
            int c = col0 + cf * 16 + r;
            b[cf] = *(const bf16x8*)&Wp[(((size_t)ks * 128 + c) * 4 + g) * 8];
        }
        #pragma unroll
        for (int rf = 0; rf < 4; rf++)
            #pragma unroll
            for (int cf = 0; cf < 4; cf++)
                acc[rf][cf] = __builtin_amdgcn_mfma_f32_16x16x32_bf16(
                    a[rf], b[cf], acc[rf][cf], 0, 0, 0);
    }
    float bv[4];
    #pragma unroll
    for (int cf = 0; cf < 4; cf++) bv[cf] = bias[col0 + cf * 16 + r];
    #pragma unroll
    for (int rf = 0; rf < 4; rf++) {
        #pragma unroll
        for (int j = 0; j < 4; j++) {
            int row = row0 + rf * 16 + g * 4 + j;
            if (row < N_NODES) {
                #pragma unroll
                for (int cf = 0; cf < 4; cf++) {
                    float v = fmaxf(acc[rf][cf][j] + bv[cf], 0.f);
                    int col = col0 + cf * 16 + r;
                    if (OUT_F32) ((float*)outv)[(size_t)row * D + col] = v;
                    else ((ushort*)outv)[(size_t)row * D + col] = f2bf(v);
                }
            }
        }
    }
}

extern "C" void kernel_launch(void* const* d_in, const int* in_sizes, int n_in,
                              void* d_out, int out_size, void* d_ws, size_t ws_size,
                              hipStream_t stream) {
    const float* x   = (const float*)d_in[0];
    const int*   ei  = (const int*)d_in[1];
    const float* Wn1 = (const float*)d_in[2];
    const float* Wr1 = (const float*)d_in[3];
    const float* b1  = (const float*)d_in[4];
    const float* Wn2 = (const float*)d_in[5];
    const float* Wr2 = (const float*)d_in[6];
    const float* b2  = (const float*)d_in[7];
    float* out = (float*)d_out;

    const int* src = ei;
    const int* dst = ei + N_EDGES;

    const size_t bfb = (size_t)N_NODES * D * 2;          // 12.8 MB
    const size_t packb = 256 * 128 * 2;                  // 64 KB
    auto au = [](size_t v) { return (v + 255) & ~(size_t)255; };

    char* w = (char*)d_ws;
    size_t o = 0;
    ushort* aggb = (ushort*)(w + o); o += au(bfb);
    ushort* hb   = (ushort*)(w + o); o += au(bfb);
    ushort* edge_src = (ushort*)(w + o); o += au((size_t)N_EDGES * 2);
    ushort* Wp2  = (ushort*)(w + o); o += au(packb);

    size_t rem = au(bfb) + au(packb) + au((N_NODES + 1) * 4ull) +
                 au(N_NODES * 4ull) + 2 * au(64 * 4);
    ushort *xb, *Wp1;
    int *row_ptr, *deg, *bsum, *boff;
    if (ws_size >= o + rem) {
        xb = (ushort*)(w + o);      o += au(bfb);
        Wp1 = (ushort*)(w + o);     o += au(packb);
        row_ptr = (int*)(w + o);    o += au((N_NODES + 1) * 4ull);
        deg = (int*)(w + o);        o += au(N_NODES * 4ull);
        bsum = (int*)(w + o);       o += au(64 * 4);
        boff = (int*)(w + o);
    } else {
        // stash build-time data in d_out; all of it is dead before the final
        // GEMM (which reads only ws + d_in) rewrites d_out in full.
        char* q = (char*)d_out;
        size_t p = 0;
        xb = (ushort*)(q + p);      p += au(bfb);
        Wp1 = (ushort*)(q + p);     p += au(packb);
        row_ptr = (int*)(q + p);    p += au((N_NODES + 1) * 4ull);
        deg = (int*)(q + p);        p += au(N_NODES * 4ull);
        bsum = (int*)(q + p);       p += au(64 * 4);
        boff = (int*)(q + p);
    }

    hipMemsetAsync(deg, 0, N_NODES * sizeof(int), stream);
    k_prep<<<CVT_BLKS + PACK_BLKS + HIST_BLKS, 256, 0, stream>>>(
        x, xb, Wn1, Wr1, Wp1, Wn2, Wr2, Wp2, dst, deg);

    const int nb = (N_NODES + 1023) / 1024;              // 49
    k_scan1<<<nb, 1024, 0, stream>>>(deg, row_ptr, bsum);
    k_scan2<<<1, 64, 0, stream>>>(bsum, boff, row_ptr + N_NODES, nb);
    k_scan3<<<nb, 1024, 0, stream>>>(row_ptr, boff);
    k_scatter<<<(N_EDGES + 255) / 256, 256, 0, stream>>>(src, dst, row_ptr, deg, edge_src);

    const int aggGrid = (N_NODES * 64) / 256;            // one wave per node
    const int gemmGrid = (N_NODES + 63) / 64;            // 782

    k_agg<<<aggGrid, 256, 0, stream>>>(xb, row_ptr, edge_src, aggb);
    k_gemm<0><<<gemmGrid, 128, 0, stream>>>(aggb, xb, Wp1, b1, hb);
    k_agg<<<aggGrid, 256, 0, stream>>>(hb, row_ptr, edge_src, aggb);
    k_gemm<1><<<gemmGrid, 128, 0, stream>>>(aggb, hb, Wp2, b2, out);
}

// Round 4
// 141.260 us; speedup vs baseline: 2.5709x; 1.3076x over previous
//
#include <hip/hip_runtime.h>

#define N_NODES 50000
#define N_EDGES 800000
#define D 128
#define NBINS 196                        // ceil(50000/256)

typedef __attribute__((ext_vector_type(8))) short bf16x8;
typedef __attribute__((ext_vector_type(4))) float f32x4;

__device__ __forceinline__ unsigned short f2bf(float f) {
    unsigned u = __float_as_uint(f);
    unsigned r = (u + 0x7FFFu + ((u >> 16) & 1u)) >> 16;   // RNE
    return (unsigned short)r;
}
__device__ __forceinline__ float bf2f(unsigned short h) {
    return __uint_as_float(((unsigned)h) << 16);
}

// ---------- fused prep: x->bf16 cvt | W packs | coarse bin count ----------
#define CVT_BLKS 3125                    // 50000*128/8 / 256
#define PACK_BLKS 128                    // 256*128 / 256
#define BINC_BLKS 391                    // ceil(800000/2048)

__device__ __forceinline__ void pack_one(const float* __restrict__ Wn,
                                         const float* __restrict__ Wr,
                                         ushort* __restrict__ Wp, int t) {
    int k = t >> 7, c = t & 127;
    float v = (k < 128) ? Wn[k * 128 + c] : Wr[(k - 128) * 128 + c];
    int ks = k >> 5, g = (k >> 3) & 3, i = k & 7;
    Wp[(((ks * 128 + c) * 4 + g) << 3) + i] = f2bf(v);
}

__global__ __launch_bounds__(256) void k_prep(const float* __restrict__ x,
                                              ushort* __restrict__ xb,
                                              const float* __restrict__ Wn1,
                                              const float* __restrict__ Wr1,
                                              ushort* __restrict__ Wp1,
                                              const float* __restrict__ Wn2,
                                              const float* __restrict__ Wr2,
                                              ushort* __restrict__ Wp2,
                                              const int* __restrict__ dst,
                                              int* __restrict__ binCnt) {
    __shared__ int lc[NBINS];
    int b = blockIdx.x;
    if (b < CVT_BLKS) {
        int i = b * 256 + threadIdx.x;               // 8 f32 per thread
        const float4* p = (const float4*)(x + (size_t)i * 8);
        float4 a = p[0], c = p[1];
        uint4 o;
        o.x = (unsigned)f2bf(a.x) | ((unsigned)f2bf(a.y) << 16);
        o.y = (unsigned)f2bf(a.z) | ((unsigned)f2bf(a.w) << 16);
        o.z = (unsigned)f2bf(c.x) | ((unsigned)f2bf(c.y) << 16);
        o.w = (unsigned)f2bf(c.z) | ((unsigned)f2bf(c.w) << 16);
        *(uint4*)(xb + (size_t)i * 8) = o;
    } else if (b < CVT_BLKS + PACK_BLKS) {
        int t = (b - CVT_BLKS) * 256 + threadIdx.x;  // 0..32767
        pack_one(Wn1, Wr1, Wp1, t);
        pack_one(Wn2, Wr2, Wp2, t);
    } else {
        const int tid = threadIdx.x;
        const int base = (b - CVT_BLKS - PACK_BLKS) * 2048;
        if (tid < NBINS) lc[tid] = 0;
        __syncthreads();
        #pragma unroll
        for (int k = 0; k < 8; k++) {
            int i = base + k * 256 + tid;
            if (i < N_EDGES) atomicAdd(&lc[dst[i] >> 8], 1);
        }
        __syncthreads();
        if (tid < NBINS) {
            int c = lc[tid];
            if (c) atomicAdd(&binCnt[tid], c);
        }
    }
}

// ---------- scan over 196 bin counts ----------
__global__ __launch_bounds__(256) void k_scanB(const int* __restrict__ binCnt,
                                               int* __restrict__ binBase,
                                               int* __restrict__ binFill,
                                               int* __restrict__ row_ptr) {
    __shared__ int ws[4];
    const int tid = threadIdx.x, lane = tid & 63, w = tid >> 6;
    int v = (tid < NBINS) ? binCnt[tid] : 0;
    int incl = v;
    #pragma unroll
    for (int off = 1; off < 64; off <<= 1) {
        int t = __shfl_up(incl, off);
        if (lane >= off) incl += t;
    }
    if (lane == 63) ws[w] = incl;
    __syncthreads();
    int wo = 0;
    if (w > 0) wo += ws[0];
    if (w > 1) wo += ws[1];
    if (w > 2) wo += ws[2];
    int excl = wo + incl - v;
    if (tid < NBINS) { binBase[tid] = excl; binFill[tid] = excl; }
    if (tid == 255) { binBase[NBINS] = excl; row_ptr[N_NODES] = excl; }
}

// ---------- phase A: bin edges into coarse dst bins (locality-friendly) ----------
__global__ __launch_bounds__(256) void k_binA(const int* __restrict__ src,
                                              const int* __restrict__ dst,
                                              int* __restrict__ binFill,
                                              unsigned* __restrict__ binned) {
    __shared__ int lc[NBINS];
    const int tid = threadIdx.x;
    const int base = blockIdx.x * 2048;
    if (tid < NBINS) lc[tid] = 0;
    __syncthreads();
    int s[8], d[8];
    #pragma unroll
    for (int k = 0; k < 8; k++) {
        int i = base + k * 256 + tid;
        if (i < N_EDGES) {
            s[k] = src[i];
            d[k] = dst[i];
            atomicAdd(&lc[d[k] >> 8], 1);
        } else d[k] = -1;
    }
    __syncthreads();
    if (tid < NBINS) {
        int c = lc[tid];
        lc[tid] = c ? atomicAdd(&binFill[tid], c) : 0;   // block's base in bin
    }
    __syncthreads();
    #pragma unroll
    for (int k = 0; k < 8; k++) {
        if (d[k] >= 0) {
            int pos = atomicAdd(&lc[d[k] >> 8], 1);
            binned[pos] = (unsigned)s[k] | ((unsigned)(d[k] & 255) << 16);
        }
    }
}

// ---------- phase B: per-bin CSR (row_ptr) + local scatter ----------
__global__ __launch_bounds__(256) void k_binB(const unsigned* __restrict__ binned,
                                              const int* __restrict__ binBase,
                                              int* __restrict__ row_ptr,
                                              ushort* __restrict__ edge_src) {
    __shared__ int cnt[256];
    __shared__ int cur[256];
    __shared__ int ws[4];
    const int tid = threadIdx.x, lane = tid & 63, w = tid >> 6;
    const int b = blockIdx.x;
    const int node0 = b << 8;
    int nNodes = N_NODES - node0; if (nNodes > 256) nNodes = 256;
    const int ebeg = binBase[b], eend = binBase[b + 1];
    cnt[tid] = 0;
    __syncthreads();
    for (int e = ebeg + tid; e < eend; e += 256) {
        unsigned rec = binned[e];
        atomicAdd(&cnt[(rec >> 16) & 255], 1);
    }
    __syncthreads();
    int v = cnt[tid];
    int incl = v;
    #pragma unroll
    for (int off = 1; off < 64; off <<= 1) {
        int t = __shfl_up(incl, off);
        if (lane >= off) incl += t;
    }
    if (lane == 63) ws[w] = incl;
    __syncthreads();
    int wo = 0;
    if (w > 0) wo += ws[0];
    if (w > 1) wo += ws[1];
    if (w > 2) wo += ws[2];
    int excl = wo + incl - v;
    cur[tid] = ebeg + excl;
    if (tid < nNodes) row_ptr[node0 + tid] = ebeg + excl;
    __syncthreads();
    for (int e = ebeg + tid; e < eend; e += 256) {
        unsigned rec = binned[e];
        int pos = atomicAdd(&cur[(rec >> 16) & 255], 1);
        edge_src[pos] = (ushort)(rec & 0xffffu);
    }
}

// ---------- mean aggregation: one wave/node, 16 lanes/edge, 4-deep MLP ----------
__global__ __launch_bounds__(256) void k_agg(const ushort* __restrict__ xb,
                                             const int* __restrict__ row_ptr,
                                             const ushort* __restrict__ edge_src,
                                             ushort* __restrict__ aggb) {
    int node = (blockIdx.x * blockDim.x + threadIdx.x) >> 6;
    int lane = threadIdx.x & 63;
    if (node >= N_NODES) return;
    int beg = row_ptr[node], end = row_ptr[node + 1];
    const int g  = lane >> 4;          // edge slot 0..3
    const int c8 = (lane & 15) * 8;    // col base
    float acc[8] = {};
    for (int e = beg; e < end; e += 16) {
        bf16x8 v[4];
        float sc[4];
        #pragma unroll
        for (int u = 0; u < 4; u++) {
            int ee = e + u * 4 + g;
            int eec = ee < end ? ee : end - 1;
            sc[u] = ee < end ? 1.f : 0.f;
            int sid = edge_src[eec];
            v[u] = *(const bf16x8*)&xb[(size_t)sid * D + c8];
        }
        #pragma unroll
        for (int u = 0; u < 4; u++)
            #pragma unroll
            for (int j = 0; j < 8; j++)
                acc[j] = fmaf(bf2f((unsigned short)v[u][j]), sc[u], acc[j]);
    }
    #pragma unroll
    for (int j = 0; j < 8; j++) acc[j] += __shfl_xor(acc[j], 16);
    #pragma unroll
    for (int j = 0; j < 8; j++) acc[j] += __shfl_xor(acc[j], 32);
    if (lane < 16) {
        int dg = end - beg;
        float inv = 1.0f / (float)(dg > 1 ? dg : 1);
        uint4 o;
        o.x = (unsigned)f2bf(acc[0] * inv) | ((unsigned)f2bf(acc[1] * inv) << 16);
        o.y = (unsigned)f2bf(acc[2] * inv) | ((unsigned)f2bf(acc[3] * inv) << 16);
        o.z = (unsigned)f2bf(acc[4] * inv) | ((unsigned)f2bf(acc[5] * inv) << 16);
        o.w = (unsigned)f2bf(acc[6] * inv) | ((unsigned)f2bf(acc[7] * inv) << 16);
        *(uint4*)&aggb[(size_t)node * D + c8] = o;
    }
}

// ---------- MFMA GEMM: out = relu([agg|xroot] @ [Wn;Wr] + b) ----------
template <int OUT_F32>
__global__ __launch_bounds__(128) void k_gemm(const ushort* __restrict__ Ab,
                                              const ushort* __restrict__ Xb,
                                              const ushort* __restrict__ Wp,
                                              const float* __restrict__ bias,
                                              void* __restrict__ outv) {
    const int lane = threadIdx.x & 63;
    const int wid  = threadIdx.x >> 6;
    const int row0 = blockIdx.x * 64;
    const int col0 = wid * 64;
    const int r = lane & 15, g = lane >> 4;

    f32x4 acc[4][4] = {};
    #pragma unroll
    for (int ks = 0; ks < 8; ks++) {
        const ushort* As = (ks < 4) ? Ab : Xb;
        const int kk = (ks & 3) * 32 + 8 * g;
        bf16x8 a[4], b[4];
        #pragma unroll
        for (int rf = 0; rf < 4; rf++) {
            int rr = row0 + rf * 16 + r;
            if (rr > N_NODES - 1) rr = N_NODES - 1;
            a[rf] = *(const bf16x8*)&As[(size_t)rr * D + kk];
        }
        #pragma unroll
        for (int cf = 0; cf < 4; cf++) {
            int c = col0 + cf * 16 + r;
            b[cf] = *(const bf16x8*)&Wp[(((size_t)ks * 128 + c) * 4 + g) * 8];
        }
        #pragma unroll
        for (int rf = 0; rf < 4; rf++)
            #pragma unroll
            for (int cf = 0; cf < 4; cf++)
                acc[rf][cf] = __builtin_amdgcn_mfma_f32_16x16x32_bf16(
                    a[rf], b[cf], acc[rf][cf], 0, 0, 0);
    }
    float bv[4];
    #pragma unroll
    for (int cf = 0; cf < 4; cf++) bv[cf] = bias[col0 + cf * 16 + r];
    #pragma unroll
    for (int rf = 0; rf < 4; rf++) {
        #pragma unroll
        for (int j = 0; j < 4; j++) {
            int row = row0 + rf * 16 + g * 4 + j;
            if (row < N_NODES) {
                #pragma unroll
                for (int cf = 0; cf < 4; cf++) {
                    float v = fmaxf(acc[rf][cf][j] + bv[cf], 0.f);
                    int col = col0 + cf * 16 + r;
                    if (OUT_F32) ((float*)outv)[(size_t)row * D + col] = v;
                    else ((ushort*)outv)[(size_t)row * D + col] = f2bf(v);
                }
            }
        }
    }
}

extern "C" void kernel_launch(void* const* d_in, const int* in_sizes, int n_in,
                              void* d_out, int out_size, void* d_ws, size_t ws_size,
                              hipStream_t stream) {
    const float* x   = (const float*)d_in[0];
    const int*   ei  = (const int*)d_in[1];
    const float* Wn1 = (const float*)d_in[2];
    const float* Wr1 = (const float*)d_in[3];
    const float* b1  = (const float*)d_in[4];
    const float* Wn2 = (const float*)d_in[5];
    const float* Wr2 = (const float*)d_in[6];
    const float* b2  = (const float*)d_in[7];
    float* out = (float*)d_out;

    const int* src = ei;
    const int* dst = ei + N_EDGES;

    const size_t bfb = (size_t)N_NODES * D * 2;          // 12.8 MB
    const size_t packb = 256 * 128 * 2;                  // 64 KB
    auto au = [](size_t v) { return (v + 255) & ~(size_t)255; };

    char* w = (char*)d_ws;
    size_t o = 0;
    ushort* aggb = (ushort*)(w + o); o += au(bfb);
    ushort* hb   = (ushort*)(w + o); o += au(bfb);
    ushort* edge_src = (ushort*)(w + o); o += au((size_t)N_EDGES * 2);
    ushort* Wp2  = (ushort*)(w + o); o += au(packb);

    const size_t binsz = au((size_t)(NBINS + NBINS + 1 + NBINS) * 4);
    size_t rem = au(bfb) + au(packb) + au((N_NODES + 1) * 4ull) +
                 au((size_t)N_EDGES * 4) + binsz;
    ushort *xb, *Wp1;
    int *row_ptr;
    unsigned* binned;
    int* bins;       // binCnt[196] | binBase[197] | binFill[196]
    if (ws_size >= o + rem) {
        xb = (ushort*)(w + o);      o += au(bfb);
        Wp1 = (ushort*)(w + o);     o += au(packb);
        row_ptr = (int*)(w + o);    o += au((N_NODES + 1) * 4ull);
        binned = (unsigned*)(w + o); o += au((size_t)N_EDGES * 4);
        bins = (int*)(w + o);
    } else {
        // stash build-time data in d_out; all of it is dead before the final
        // GEMM (which reads only ws + d_in) rewrites d_out in full.
        char* q = (char*)d_out;
        size_t p = 0;
        xb = (ushort*)(q + p);      p += au(bfb);
        Wp1 = (ushort*)(q + p);     p += au(packb);
        row_ptr = (int*)(q + p);    p += au((N_NODES + 1) * 4ull);
        binned = (unsigned*)(q + p); p += au((size_t)N_EDGES * 4);
        bins = (int*)(q + p);
    }
    int* binCnt  = bins;
    int* binBase = bins + NBINS;
    int* binFill = bins + NBINS + NBINS + 1;

    hipMemsetAsync(binCnt, 0, NBINS * sizeof(int), stream);
    k_prep<<<CVT_BLKS + PACK_BLKS + BINC_BLKS, 256, 0, stream>>>(
        x, xb, Wn1, Wr1, Wp1, Wn2, Wr2, Wp2, dst, binCnt);
    k_scanB<<<1, 256, 0, stream>>>(binCnt, binBase, binFill, row_ptr);
    k_binA<<<BINC_BLKS, 256, 0, stream>>>(src, dst, binFill, binned);
    k_binB<<<NBINS, 256, 0, stream>>>(binned, binBase, row_ptr, edge_src);

    const int aggGrid = (N_NODES * 64) / 256;            // one wave per node
    const int gemmGrid = (N_NODES + 63) / 64;            // 782

    k_agg<<<aggGrid, 256, 0, stream>>>(xb, row_ptr, edge_src, aggb);
    k_gemm<0><<<gemmGrid, 128, 0, stream>>>(aggb, xb, Wp1, b1, hb);
    k_agg<<<aggGrid, 256, 0, stream>>>(hb, row_ptr, edge_src, aggb);
    k_gemm<1><<<gemmGrid, 128, 0, stream>>>(aggb, hb, Wp2, b2, out);
}